// Round 4
// baseline (139.620 us; speedup 1.0000x reference)
//
#include <hip/hip_runtime.h>
#include <math.h>

static constexpr int M = 4096;   // batch rows
static constexpr int C = 512;    // classes
static constexpr int D = 128;    // feature dim
static constexpr float ALPHA = 0.5f;

// ---------------- workspace layout (bytes) ----------------
// label     : int[M]      @ 0       fully written by k_labelinit
// tile_cnt  : uint[64]    @ 16384   zeroed by k_labelinit (only init needed)
// d_pos     : float[M]    @ 16640   plain-stored by unique owner block
// loss_part : float[M*8]  @ 33024   plain-stored, one slot per (m, c-chunk)
static constexpr size_t WS_LABEL = 0;
static constexpr size_t WS_TCNT  = 16384;
static constexpr size_t WS_DPOS  = 16640;
static constexpr size_t WS_LPART = 33024;

// ---- kernel A: per-row argmax of onehot -> label[M]; zero tile counters ----
__global__ __launch_bounds__(256) void k_labelinit(
    const float* __restrict__ onehot, int* __restrict__ label,
    unsigned int* __restrict__ tile_cnt)
{
    int gtid = blockIdx.x * 256 + threadIdx.x;
    if (gtid < 64) tile_cnt[gtid] = 0u;

    int row  = gtid >> 6;            // grid = M/4 blocks -> row always < M
    int lane = threadIdx.x & 63;

    const float4* oh = reinterpret_cast<const float4*>(onehot + (size_t)row * C);
    float4 a = oh[lane * 2 + 0];
    float4 b = oh[lane * 2 + 1];
    int lbl = -1;
    if (a.x > 0.5f) lbl = lane * 8 + 0;
    if (a.y > 0.5f) lbl = lane * 8 + 1;
    if (a.z > 0.5f) lbl = lane * 8 + 2;
    if (a.w > 0.5f) lbl = lane * 8 + 3;
    if (b.x > 0.5f) lbl = lane * 8 + 4;
    if (b.y > 0.5f) lbl = lane * 8 + 5;
    if (b.z > 0.5f) lbl = lane * 8 + 6;
    if (b.w > 0.5f) lbl = lane * 8 + 7;
    #pragma unroll
    for (int off = 32; off > 0; off >>= 1)
        lbl = max(lbl, __shfl_xor(lbl, off));
    if (lane == 0) label[row] = lbl;
}

// ---- kernel B: prefetch tiles -> center update (class b) -> L1-distance
//      tile (mb,cb) -> last-block loss finalize ----
// grid = 512 blocks x 256 threads (2 blocks/CU, 64 KB LDS each).
__global__ __launch_bounds__(256) void k_fused(
    const float* __restrict__ x0, const float* __restrict__ centers,
    const int* __restrict__ label,
    float* __restrict__ d_pos, float* __restrict__ loss_part,
    unsigned int* __restrict__ tile_cnt,
    float* __restrict__ out_nc, float* __restrict__ loss_out)
{
    // LDS: two 64x128 f32 tiles, row-major, XOR-swizzled at quad granularity.
    // phase-1 scratch (list/tmp/lcount) aliases cs rows 0..9 (dead by staging).
    __shared__ float xs[64 * 128];
    __shared__ float cs[64 * 128];

    int tid = threadIdx.x;
    int b   = blockIdx.x;
    int mb  = b & 63, cb = b >> 6;
    int m0  = mb * 64, c0 = cb * 64;

    // ===== prefetch: issue all tile loads now; consumed after phase 1 =====
    // logical element (row, q) lives at physical quad (row*32 + q') with
    // q' = q ^ ((row>>2)&7); we pre-swizzle the GLOBAL address so the LDS
    // write below is linear (conflict-free b128), per guide m173 pattern.
    float4 px[8], pc[8];
    #pragma unroll
    for (int kk = 0; kk < 8; ++kk) {
        int Q   = kk * 256 + tid;          // physical quad index 0..2047
        int row = Q >> 5;                  // 0..63
        int ql  = (Q & 31) ^ ((row >> 2) & 7);
        px[kk] = *reinterpret_cast<const float4*>(
            x0      + (size_t)(m0 + row) * D + ql * 4);
        pc[kk] = *reinterpret_cast<const float4*>(
            centers + (size_t)(c0 + row) * D + ql * 4);
    }

    // ===== phase 1: center update for class c = b =====
    int*   list   = reinterpret_cast<int*>(cs);   // cs[0..1023]
    float* tmp    = cs + 1024;                    // cs[1024..1151]
    int*   lcount = reinterpret_cast<int*>(cs) + 1152;

    if (tid == 0) *lcount = 0;
    __syncthreads();
    {
        const int4* lab4 = reinterpret_cast<const int4*>(label);
        #pragma unroll
        for (int t = 0; t < 4; ++t) {
            int4 v   = lab4[tid + 256 * t];
            int base = (tid + 256 * t) * 4;
            if (v.x == b) { int k = atomicAdd(lcount, 1); if (k < 1024) list[k] = base + 0; }
            if (v.y == b) { int k = atomicAdd(lcount, 1); if (k < 1024) list[k] = base + 1; }
            if (v.z == b) { int k = atomicAdd(lcount, 1); if (k < 1024) list[k] = base + 2; }
            if (v.w == b) { int k = atomicAdd(lcount, 1); if (k < 1024) list[k] = base + 3; }
        }
    }
    __syncthreads();
    {
        int n = *lcount;
        int d = tid & 127;
        int p = tid >> 7;                  // 0/1: even/odd member indices
        float s = 0.f;
        int i = p;
        // unrolled 4x: keep 4 loads in flight per s_waitcnt instead of 1
        for (; i + 6 < n; i += 8) {
            float a0 = x0[(size_t)list[i + 0] * D + d];
            float a1 = x0[(size_t)list[i + 2] * D + d];
            float a2 = x0[(size_t)list[i + 4] * D + d];
            float a3 = x0[(size_t)list[i + 6] * D + d];
            s += (a0 + a1) + (a2 + a3);
        }
        for (; i < n; i += 2) s += x0[(size_t)list[i] * D + d];
        if (p == 1) tmp[d] = s;
        __syncthreads();
        if (p == 0) {
            s += tmp[d];
            float ctr = centers[b * D + d];
            out_nc[b * D + d] = ctr - ALPHA * ((float)n * ctr - s) / ((float)n + 1.0f);
        }
    }
    __syncthreads();   // phase-1 LDS scratch dead; safe to overwrite cs

    // ===== stage tiles: linear b128 writes (source was pre-swizzled) =====
    #pragma unroll
    for (int kk = 0; kk < 8; ++kk) {
        int e = (kk * 256 + tid) * 4;
        *reinterpret_cast<float4*>(xs + e) = px[kk];
        *reinterpret_cast<float4*>(cs + e) = pc[kk];
    }
    __syncthreads();

    // ===== phase 2: 64x64 L1-distance tile, 4m x 4c per thread =====
    int tx = tid & 15;          // -> 4 c rows
    int ty = tid >> 4;          // -> 4 m rows
    int xk = ty & 7;            // row-group swizzle key for x reads (broadcast)
    int ck = tx & 7;            // row-group swizzle key for c reads (2-way max)
    int xb[4], cbs[4];
    #pragma unroll
    for (int i = 0; i < 4; ++i) {
        xb[i]  = (ty * 4 + i) * 128;
        cbs[i] = (tx * 4 + i) * 128;
    }

    float acc[4][4];
    #pragma unroll
    for (int i = 0; i < 4; i++)
        #pragma unroll
        for (int j = 0; j < 4; j++) acc[i][j] = 0.f;

    #pragma unroll 8
    for (int q = 0; q < 32; ++q) {
        int xo = (q ^ xk) << 2;
        int co = (q ^ ck) << 2;
        float4 xa[4], ca[4];
        #pragma unroll
        for (int i = 0; i < 4; ++i)
            xa[i] = *reinterpret_cast<const float4*>(xs + xb[i] + xo);
        #pragma unroll
        for (int j = 0; j < 4; ++j)
            ca[j] = *reinterpret_cast<const float4*>(cs + cbs[j] + co);
        #pragma unroll
        for (int i = 0; i < 4; ++i)
            #pragma unroll
            for (int j = 0; j < 4; ++j) {
                acc[i][j] += fabsf(xa[i].x - ca[j].x);   // v_sub + v_add(|mod|)
                acc[i][j] += fabsf(xa[i].y - ca[j].y);
                acc[i][j] += fabsf(xa[i].z - ca[j].z);
                acc[i][j] += fabsf(xa[i].w - ca[j].w);
            }
    }

    // ===== epilogue: d_pos (unique owner) + per-chunk exp-sum partials =====
    {
        int lbls[4];
        #pragma unroll
        for (int i = 0; i < 4; i++) lbls[i] = label[m0 + ty * 4 + i];

        #pragma unroll
        for (int i = 0; i < 4; i++) {
            float ps = 0.f;
            #pragma unroll
            for (int j = 0; j < 4; j++) {
                int cg = c0 + tx * 4 + j;
                float dist = acc[i][j];
                if (cg == lbls[i]) {
                    d_pos[m0 + ty * 4 + i] = dist;       // unique writer per m
                } else {
                    ps += __expf(-dist);
                }
            }
            #pragma unroll
            for (int off = 8; off > 0; off >>= 1)        // 16-lane tx group
                ps += __shfl_xor(ps, off);
            if (tx == 0)
                loss_part[(size_t)(m0 + ty * 4 + i) * 8 + cb] = ps;
        }
    }

    // ===== phase 3: last block of this m-tile finalizes its 64 losses =====
    __threadfence();             // release: stores above visible device-wide
    __syncthreads();
    int* flag = reinterpret_cast<int*>(xs);   // xs dead after compute
    if (tid == 0) {
        unsigned int old = atomicAdd(&tile_cnt[mb], 1u);
        *flag = (old == 7u) ? 1 : 0;
    }
    __syncthreads();
    if (*flag && tid < 64) {
        __threadfence();         // acquire: see other blocks' stores
        int m = m0 + tid;
        float dp = __hip_atomic_load(&d_pos[m], __ATOMIC_RELAXED,
                                     __HIP_MEMORY_SCOPE_AGENT);
        float S = 0.f;
        #pragma unroll
        for (int k = 0; k < 8; ++k)
            S += __hip_atomic_load(&loss_part[(size_t)m * 8 + k],
                                   __ATOMIC_RELAXED, __HIP_MEMORY_SCOPE_AGENT);
        loss_out[m] = dp + log1pf(S);
    }
}

extern "C" void kernel_launch(void* const* d_in, const int* in_sizes, int n_in,
                              void* d_out, int out_size, void* d_ws, size_t ws_size,
                              hipStream_t stream)
{
    const float* x0      = (const float*)d_in[0];   // (M, D)
    const float* onehot  = (const float*)d_in[1];   // (M, C)
    const float* centers = (const float*)d_in[2];   // (C, D)
    float* out = (float*)d_out;                     // [0..M) loss, [M..) new_centers

    char* ws = (char*)d_ws;
    int*          label     = (int*)          (ws + WS_LABEL);
    unsigned int* tile_cnt  = (unsigned int*) (ws + WS_TCNT);
    float*        d_pos     = (float*)        (ws + WS_DPOS);
    float*        loss_part = (float*)        (ws + WS_LPART);

    k_labelinit<<<M / 4, 256, 0, stream>>>(onehot, label, tile_cnt);
    k_fused    <<<512,   256, 0, stream>>>(x0, centers, label, d_pos, loss_part,
                                           tile_cnt, out + M, out);
}

// Round 5
// 91.420 us; speedup vs baseline: 1.5272x; 1.5272x over previous
//
#include <hip/hip_runtime.h>
#include <math.h>

static constexpr int M = 4096;   // batch rows
static constexpr int C = 512;    // classes
static constexpr int D = 128;    // feature dim
static constexpr float ALPHA = 0.5f;

// ---------------- workspace layout (bytes) ----------------
// label     : int[M]      @ 0       fully written by k_label
// d_pos     : float[M]    @ 16384   plain-stored by unique owner thread
// loss_part : float[M*8]  @ 33024   plain-stored, one slot per (m, c-chunk)
// no zero-init needed anywhere.
static constexpr size_t WS_LABEL = 0;
static constexpr size_t WS_DPOS  = 16384;
static constexpr size_t WS_LPART = 33024;

// ---- kernel 1: per-row argmax of onehot -> label[M] ----
__global__ __launch_bounds__(256) void k_label(
    const float* __restrict__ onehot, int* __restrict__ label)
{
    int gtid = blockIdx.x * 256 + threadIdx.x;
    int row  = gtid >> 6;            // grid = M/4 -> row < M always
    int lane = threadIdx.x & 63;

    const float4* oh = reinterpret_cast<const float4*>(onehot + (size_t)row * C);
    float4 a = oh[lane * 2 + 0];
    float4 b = oh[lane * 2 + 1];
    int lbl = -1;
    if (a.x > 0.5f) lbl = lane * 8 + 0;
    if (a.y > 0.5f) lbl = lane * 8 + 1;
    if (a.z > 0.5f) lbl = lane * 8 + 2;
    if (a.w > 0.5f) lbl = lane * 8 + 3;
    if (b.x > 0.5f) lbl = lane * 8 + 4;
    if (b.y > 0.5f) lbl = lane * 8 + 5;
    if (b.z > 0.5f) lbl = lane * 8 + 6;
    if (b.w > 0.5f) lbl = lane * 8 + 7;
    #pragma unroll
    for (int off = 32; off > 0; off >>= 1)
        lbl = max(lbl, __shfl_xor(lbl, off));
    if (lane == 0) label[row] = lbl;
}

// ---- kernel 2: per-class center update (block c = class c) ----
// LDS member list, then 2x128 threads gather-sum member rows along d.
// Side effect: collectively reads every x0 row once -> warms L2/L3 for k_dist.
__global__ __launch_bounds__(256) void k_newc(
    const float* __restrict__ x0, const float* __restrict__ centers,
    const int* __restrict__ label, float* __restrict__ out_nc)
{
    __shared__ int   list[1024];
    __shared__ float tmp[128];
    __shared__ int   lcount;
    int c   = blockIdx.x;
    int tid = threadIdx.x;
    if (tid == 0) lcount = 0;
    __syncthreads();

    const int4* lab4 = reinterpret_cast<const int4*>(label);
    #pragma unroll
    for (int t = 0; t < 4; ++t) {
        int4 v   = lab4[tid + 256 * t];
        int base = (tid + 256 * t) * 4;
        if (v.x == c) { int k = atomicAdd(&lcount, 1); if (k < 1024) list[k] = base + 0; }
        if (v.y == c) { int k = atomicAdd(&lcount, 1); if (k < 1024) list[k] = base + 1; }
        if (v.z == c) { int k = atomicAdd(&lcount, 1); if (k < 1024) list[k] = base + 2; }
        if (v.w == c) { int k = atomicAdd(&lcount, 1); if (k < 1024) list[k] = base + 3; }
    }
    __syncthreads();

    int n = lcount;
    int d = tid & 127;
    int p = tid >> 7;                  // 0/1: even/odd member indices
    float s = 0.f;
    int i = p;
    for (; i + 6 < n; i += 8) {        // 4 loads in flight per wait
        float a0 = x0[(size_t)list[i + 0] * D + d];
        float a1 = x0[(size_t)list[i + 2] * D + d];
        float a2 = x0[(size_t)list[i + 4] * D + d];
        float a3 = x0[(size_t)list[i + 6] * D + d];
        s += (a0 + a1) + (a2 + a3);
    }
    for (; i < n; i += 2) s += x0[(size_t)list[i] * D + d];
    if (p == 1) tmp[d] = s;
    __syncthreads();
    if (p == 0) {
        s += tmp[d];
        float ctr = centers[c * D + d];
        out_nc[c * D + d] = ctr - ALPHA * ((float)n * ctr - s) / ((float)n + 1.0f);
    }
}

// ---- kernel 3: 64x64 L1-distance tile + exp-sum partials + d_pos ----
// grid: 64 m-tiles x 8 c-chunks = 512 blocks, 256 threads, 32 KB LDS.
// LDS layout per chunk: row-major [64 rows][16 quads], physical quad p holds
// logical quad q = p ^ ((row>>2)&7); swizzle applied to the GLOBAL source
// address so LDS writes are linear b128 (conflict-free); reads use the same
// key: c-side 2-way max (free), x-side 4-address broadcast (free).
__global__ __launch_bounds__(256) void k_dist(
    const float* __restrict__ x0, const float* __restrict__ centers,
    const int* __restrict__ label,
    float* __restrict__ d_pos, float* __restrict__ loss_part)
{
    __shared__ float xs[64 * 64];    // 16 KB
    __shared__ float cs[64 * 64];    // 16 KB

    int tid = threadIdx.x;
    int mb = blockIdx.x & 63;   // m tile
    int cb = blockIdx.x >> 6;   // c chunk
    int m0 = mb * 64, c0 = cb * 64;
    int tx = tid & 15;          // -> 4 c rows
    int ty = tid >> 4;          // -> 4 m rows
    int xk = ty & 7;            // read-swizzle key for x rows (ty*4+i)>>2 == ty
    int ck = tx & 7;            // read-swizzle key for c rows

    float acc[4][4];
    #pragma unroll
    for (int i = 0; i < 4; i++)
        #pragma unroll
        for (int j = 0; j < 4; j++) acc[i][j] = 0.f;

    for (int dc = 0; dc < 2; ++dc) {
        int d0 = dc * 64;
        __syncthreads();   // protect LDS from previous iteration's readers
        // stage: 1024 quads per side; thread covers 4 physical quads each side
        #pragma unroll
        for (int kk = 0; kk < 4; ++kk) {
            int Q   = kk * 256 + tid;          // physical quad index 0..1023
            int row = Q >> 4;                  // 0..63
            int q   = (Q & 15) ^ ((row >> 2) & 7);   // logical quad
            float4 vx = *reinterpret_cast<const float4*>(
                x0      + (size_t)(m0 + row) * D + d0 + q * 4);
            float4 vc = *reinterpret_cast<const float4*>(
                centers + (size_t)(c0 + row) * D + d0 + q * 4);
            *reinterpret_cast<float4*>(xs + Q * 4) = vx;   // linear: no conflict
            *reinterpret_cast<float4*>(cs + Q * 4) = vc;
        }
        __syncthreads();

        #pragma unroll 4
        for (int q = 0; q < 16; ++q) {
            int xo = (q ^ xk) << 2;
            int co = (q ^ ck) << 2;
            float4 xa[4], ca[4];
            #pragma unroll
            for (int i = 0; i < 4; ++i)
                xa[i] = *reinterpret_cast<const float4*>(xs + (ty * 4 + i) * 64 + xo);
            #pragma unroll
            for (int j = 0; j < 4; ++j)
                ca[j] = *reinterpret_cast<const float4*>(cs + (tx * 4 + j) * 64 + co);
            #pragma unroll
            for (int i = 0; i < 4; ++i)
                #pragma unroll
                for (int j = 0; j < 4; ++j) {
                    acc[i][j] += fabsf(xa[i].x - ca[j].x);   // v_sub+v_add(|mod|)
                    acc[i][j] += fabsf(xa[i].y - ca[j].y);
                    acc[i][j] += fabsf(xa[i].z - ca[j].z);
                    acc[i][j] += fabsf(xa[i].w - ca[j].w);
                }
        }
    }

    // epilogue: d_pos (unique owner) + per-chunk exp-sum partials
    int lbls[4];
    #pragma unroll
    for (int i = 0; i < 4; i++) lbls[i] = label[m0 + ty * 4 + i];

    #pragma unroll
    for (int i = 0; i < 4; i++) {
        float ps = 0.f;
        #pragma unroll
        for (int j = 0; j < 4; j++) {
            int cg = c0 + tx * 4 + j;
            float dist = acc[i][j];
            if (cg == lbls[i]) {
                d_pos[m0 + ty * 4 + i] = dist;        // unique writer per m
            } else {
                ps += __expf(-dist);
            }
        }
        #pragma unroll
        for (int off = 8; off > 0; off >>= 1)         // 16-lane tx group
            ps += __shfl_xor(ps, off);
        if (tx == 0)
            loss_part[(size_t)(m0 + ty * 4 + i) * 8 + cb] = ps;
    }
}

// ---- kernel 4: loss[m] = d_pos[m] + log1p(sum of 8 chunk partials) ----
__global__ __launch_bounds__(256) void k_fin(
    const float* __restrict__ d_pos, const float* __restrict__ loss_part,
    float* __restrict__ loss_out)
{
    int m = blockIdx.x * 256 + threadIdx.x;
    if (m >= M) return;
    const float4* p = reinterpret_cast<const float4*>(loss_part + (size_t)m * 8);
    float4 a = p[0], b = p[1];
    float s = (a.x + a.y) + (a.z + a.w) + (b.x + b.y) + (b.z + b.w);
    loss_out[m] = d_pos[m] + log1pf(s);
}

extern "C" void kernel_launch(void* const* d_in, const int* in_sizes, int n_in,
                              void* d_out, int out_size, void* d_ws, size_t ws_size,
                              hipStream_t stream)
{
    const float* x0      = (const float*)d_in[0];   // (M, D)
    const float* onehot  = (const float*)d_in[1];   // (M, C)
    const float* centers = (const float*)d_in[2];   // (C, D)
    float* out = (float*)d_out;                     // [0..M) loss, [M..) new_centers

    char* ws = (char*)d_ws;
    int*   label     = (int*)  (ws + WS_LABEL);
    float* d_pos     = (float*)(ws + WS_DPOS);
    float* loss_part = (float*)(ws + WS_LPART);

    k_label<<<M / 4,   256, 0, stream>>>(onehot, label);
    k_newc <<<C,       256, 0, stream>>>(x0, centers, label, out + M);
    k_dist <<<512,     256, 0, stream>>>(x0, centers, label, d_pos, loss_part);
    k_fin  <<<M / 256, 256, 0, stream>>>(d_pos, loss_part, out);
}